// Round 7
// baseline (341.721 us; speedup 1.0000x reference)
//
#include <hip/hip_runtime.h>

// SCVC: out[n, g*OG+o, p, q] = C[g,o]*x[n,g,p]*y[n,g,q]
//                              + wA[g,o,0]*x[n,g,p-1] + wA[g,o,1]*x[n,g,p+1]
//                              + wB[g,o,0]*y[n,g,q-1] + wB[g,o,1]*y[n,g,q+1]
// Shapes: N=8, G=8, OG=16, DX=DY=256. Output fp32, 256 MiB.
//
// Evidence ledger (timed region = 1 GiB poison fill @6.6 TB/s ~162 us fixed
// + kernel):
//   R3 ~98 | R4 ~93 (best) | R5 sweep ~124 | R6 256blk ~97 | R7 nt ~96
//   R8 two-pass diagnostic: kernel ~120.7 us -> Theory S (intrinsic 2.9
//   TB/s at our geometry) FALSIFIED: warm second pass ran ~38 us (~6.7
//   TB/s-equiv). Pass 1 into poison-dirty hierarchy = 82-93 us.
// Remaining theories are counter-distinguishable, but the kernel row has
// NEVER appeared in top-5 (fills ~160-169 us monopolize it).
//
// R9 = COUNTER-CAPTURE DIAGNOSTIC (regression by design; revert after).
// 3 zero-store passes + 1 compute pass over identical addresses ->
// kernel ~200 us -> enters top-5 WITH its FETCH_SIZE/WRITE_SIZE/VALUBusy.
// Pre-committed readings:
//   FETCH >= ~262144 KB            -> RFO on first touch -> asm nt stores
//   FETCH tiny, WRITE >= ~400000   -> poison-victim evictions
//   FETCH tiny, WRITE ~262144, VALUBusy>50 -> issue-bound -> strip loop
//   dur ~530                       -> R8 decomposition wrong; re-model
// Predicted dur_us ~355-375.

#define N_  8
#define G_  8
#define OG_ 16
#define DX_ 256
#define DY_ 256

typedef float vfloat4 __attribute__((ext_vector_type(4)));

__global__ __launch_bounds__(256) void scvc_kernel(
    const float* __restrict__ x,   // (N, G, DX)
    const float* __restrict__ y,   // (N, G, DY)
    const float* __restrict__ C,   // (G, OG)
    const float* __restrict__ wA,  // (G, OG, 2)
    const float* __restrict__ wB,  // (G, OG, 2)
    float* __restrict__ out)       // (N, G*OG, DX, DY)
{
    __shared__ float sarr[DX_];   // C[g,o] * x[n,g,p]
    __shared__ float aarr[DX_];   // wA0*x[p-1] + wA1*x[p+1]
    __shared__ float ybuf[DY_];   // y[n,g,q]
    __shared__ float bbuf[DY_];   // wB0*y[q-1] + wB1*y[q+1]

    const int t    = blockIdx.x >> 1;        // channel index 0 .. N*G*OG-1
    const int half = blockIdx.x & 1;         // which 128-row half of the image
    const int n   = t / (G_ * OG_);
    const int rem = t % (G_ * OG_);
    const int g   = rem / OG_;
    const int o   = rem % OG_;

    const int tid = threadIdx.x;

    const int go = g * OG_ + o;
    const float co  = C[go];
    const float wa0 = wA[go * 2 + 0];
    const float wa1 = wA[go * 2 + 1];
    const float wb0 = wB[go * 2 + 0];
    const float wb1 = wB[go * 2 + 1];

    const float* xrow = x + (size_t)(n * G_ + g) * DX_;
    const float* yrow = y + (size_t)(n * G_ + g) * DY_;

    // One-time per-block staging (256 threads cover DX_=DY_=256).
    {
        float xv = xrow[tid];
        float xl = (tid > 0)       ? xrow[tid - 1] : 0.0f;
        float xr = (tid < DX_ - 1) ? xrow[tid + 1] : 0.0f;
        sarr[tid] = co * xv;
        aarr[tid] = fmaf(wa0, xl, wa1 * xr);

        float yv = yrow[tid];
        float yl = (tid > 0)       ? yrow[tid - 1] : 0.0f;
        float yr = (tid < DY_ - 1) ? yrow[tid + 1] : 0.0f;
        ybuf[tid] = yv;
        bbuf[tid] = fmaf(wb0, yl, wb1 * yr);
    }
    __syncthreads();

    const int qv = tid & 63;
    const int wv = tid >> 6;                 // wave id 0..3
    const int p0 = half * (DX_ / 2) + wv * 32;

    const vfloat4 y4 = ((const vfloat4*)ybuf)[qv];
    const vfloat4 b4 = ((const vfloat4*)bbuf)[qv];

    float* obase = out + (size_t)t * (DX_ * DY_) + (size_t)p0 * DY_;

    // ---- PASSES 1-3: zero-store passes over the exact output addresses.
    // Pass 1 = cold first-touch into poison-dirty hierarchy; passes 2-3 =
    // warm repeats (internal consistency check). Overwritten by the final
    // compute pass -> correctness preserved.
    for (int pass = 0; pass < 3; ++pass) {
        vfloat4 z;
        z.x = 0.0f; z.y = 0.0f; z.z = 0.0f; z.w = 0.0f;
#pragma unroll 4
        for (int i = 0; i < 32; ++i) {
            ((vfloat4*)(obase + (size_t)i * DY_))[qv] = z;
        }
        asm volatile("" ::: "memory");  // no DSE / pass merging
    }

    // ---- FINAL PASS: normal compute + store (identical to R4).
#pragma unroll 4
    for (int i = 0; i < 32; ++i) {
        const int p  = p0 + i;
        const float s  = sarr[p];
        const float av = aarr[p];
        vfloat4 v;
        v.x = fmaf(s, y4.x, av + b4.x);
        v.y = fmaf(s, y4.y, av + b4.y);
        v.z = fmaf(s, y4.z, av + b4.z);
        v.w = fmaf(s, y4.w, av + b4.w);
        ((vfloat4*)(obase + (size_t)i * DY_))[qv] = v;
    }
}

extern "C" void kernel_launch(void* const* d_in, const int* in_sizes, int n_in,
                              void* d_out, int out_size, void* d_ws, size_t ws_size,
                              hipStream_t stream) {
    const float* x  = (const float*)d_in[0];
    const float* y  = (const float*)d_in[1];
    const float* C  = (const float*)d_in[2];
    const float* wA = (const float*)d_in[3];
    const float* wB = (const float*)d_in[4];
    float* out = (float*)d_out;

    const int nblocks = N_ * G_ * OG_ * 2;  // 2048
    scvc_kernel<<<nblocks, 256, 0, stream>>>(x, y, C, wA, wB, out);
}

// Round 8
// 265.662 us; speedup vs baseline: 1.2863x; 1.2863x over previous
//
#include <hip/hip_runtime.h>

// SCVC: out[n, g*OG+o, p, q] = C[g,o]*x[n,g,p]*y[n,g,q]
//                              + wA[g,o,0]*x[n,g,p-1] + wA[g,o,1]*x[n,g,p+1]
//                              + wB[g,o,0]*y[n,g,q-1] + wB[g,o,1]*y[n,g,q+1]
// Shapes: N=8, G=8, OG=16, DX=DY=256. Output fp32, 256 MiB.
//
// Evidence ledger (timed = 1 GiB poison fill ~162 us fixed + kernel):
//   R3 ~98 | R4 ~93 (best) | R5 sweep ~124 | R6 256blk ~97 | R7 builtin-nt ~96
//   R8 (2 passes) ~120.7 | R9 (4 passes) ~180
// Linear decomposition: COLD first-touch pass ~92 us (2.9 TB/s), warm
// passes ~29 us (~9 TB/s, cache-absorbed). Zero-cold == compute-cold ->
// compute/LDS/input side exonerated. Bottleneck = L3 allocate ->
// dirty-victim-evict serialization on first touch. Fill proves the HW does
// 6.6 TB/s allocate+evict; warm passes prove issue path does 9 TB/s.
//
// R10: last untested axis = real cache-policy bits. __builtin_nontemporal
// sets only `nt` (null). This round: inline-asm global_store_dwordx4 with
// `sc1 nt` (system-scope non-temporal = streaming/no-allocate hint on
// gfx950). If stores bypass L2/L3 allocation, no victim eviction on the
// critical path: 256 MiB direct ~41 us.
// Pre-committed: dur <=230 streaming works; ~255 policy axis closed (one
// retest left: phase-banded window, else ROOFLINE); >=275 sc1 serializes,
// revert to R4.

#define N_  8
#define G_  8
#define OG_ 16
#define DX_ 256
#define DY_ 256

typedef float vfloat4 __attribute__((ext_vector_type(4)));

__global__ __launch_bounds__(256) void scvc_kernel(
    const float* __restrict__ x,   // (N, G, DX)
    const float* __restrict__ y,   // (N, G, DY)
    const float* __restrict__ C,   // (G, OG)
    const float* __restrict__ wA,  // (G, OG, 2)
    const float* __restrict__ wB,  // (G, OG, 2)
    float* __restrict__ out)       // (N, G*OG, DX, DY)
{
    __shared__ float sarr[DX_];   // C[g,o] * x[n,g,p]
    __shared__ float aarr[DX_];   // wA0*x[p-1] + wA1*x[p+1]
    __shared__ float ybuf[DY_];   // y[n,g,q]
    __shared__ float bbuf[DY_];   // wB0*y[q-1] + wB1*y[q+1]

    const int t    = blockIdx.x >> 1;        // channel index 0 .. N*G*OG-1
    const int half = blockIdx.x & 1;         // which 128-row half of the image
    const int n   = t / (G_ * OG_);
    const int rem = t % (G_ * OG_);
    const int g   = rem / OG_;
    const int o   = rem % OG_;

    const int tid = threadIdx.x;

    const int go = g * OG_ + o;
    const float co  = C[go];
    const float wa0 = wA[go * 2 + 0];
    const float wa1 = wA[go * 2 + 1];
    const float wb0 = wB[go * 2 + 0];
    const float wb1 = wB[go * 2 + 1];

    const float* xrow = x + (size_t)(n * G_ + g) * DX_;
    const float* yrow = y + (size_t)(n * G_ + g) * DY_;

    // One-time per-block staging (256 threads cover DX_=DY_=256).
    {
        float xv = xrow[tid];
        float xl = (tid > 0)       ? xrow[tid - 1] : 0.0f;
        float xr = (tid < DX_ - 1) ? xrow[tid + 1] : 0.0f;
        sarr[tid] = co * xv;
        aarr[tid] = fmaf(wa0, xl, wa1 * xr);

        float yv = yrow[tid];
        float yl = (tid > 0)       ? yrow[tid - 1] : 0.0f;
        float yr = (tid < DY_ - 1) ? yrow[tid + 1] : 0.0f;
        ybuf[tid] = yv;
        bbuf[tid] = fmaf(wb0, yl, wb1 * yr);
    }
    __syncthreads();

    // Each thread owns a float4 at q = qv*4 (registers). Wave wv owns 32
    // CONTIGUOUS rows -> per-wave store stream is sequential (32 KB run).
    const int qv = tid & 63;
    const int wv = tid >> 6;                 // wave id 0..3
    const int p0 = half * (DX_ / 2) + wv * 32;

    const vfloat4 y4 = ((const vfloat4*)ybuf)[qv];
    const vfloat4 b4 = ((const vfloat4*)bbuf)[qv];

    float* obase = out + (size_t)t * (DX_ * DY_) + (size_t)p0 * DY_;

#pragma unroll 4
    for (int i = 0; i < 32; ++i) {
        const int p  = p0 + i;
        const float s  = sarr[p];
        const float av = aarr[p];
        vfloat4 v;
        v.x = fmaf(s, y4.x, av + b4.x);
        v.y = fmaf(s, y4.y, av + b4.y);
        v.z = fmaf(s, y4.z, av + b4.z);
        v.w = fmaf(s, y4.w, av + b4.w);
        // Streaming store: system-scope non-temporal (no L2/L3 allocate
        // hint). __builtin_nontemporal_store emits only `nt` (tested null,
        // R7); this adds sc1.
        vfloat4* dst = &((vfloat4*)(obase + (size_t)i * DY_))[qv];
        asm volatile("global_store_dwordx4 %0, %1, off sc1 nt"
                     :
                     : "v"(dst), "v"(v)
                     : "memory");
    }
}

extern "C" void kernel_launch(void* const* d_in, const int* in_sizes, int n_in,
                              void* d_out, int out_size, void* d_ws, size_t ws_size,
                              hipStream_t stream) {
    const float* x  = (const float*)d_in[0];
    const float* y  = (const float*)d_in[1];
    const float* C  = (const float*)d_in[2];
    const float* wA = (const float*)d_in[3];
    const float* wB = (const float*)d_in[4];
    float* out = (float*)d_out;

    const int nblocks = N_ * G_ * OG_ * 2;  // 2048
    scvc_kernel<<<nblocks, 256, 0, stream>>>(x, y, C, wA, wB, out);
}

// Round 9
// 263.247 us; speedup vs baseline: 1.2981x; 1.0092x over previous
//
#include <hip/hip_runtime.h>

// SCVC: out[n, g*OG+o, p, q] = C[g,o]*x[n,g,p]*y[n,g,q]
//                              + wA[g,o,0]*x[n,g,p-1] + wA[g,o,1]*x[n,g,p+1]
//                              + wB[g,o,0]*y[n,g,q-1] + wB[g,o,1]*y[n,g,q+1]
// Shapes: N=8, G=8, OG=16, DX=DY=256. Output fp32, 256 MiB.
//
// Evidence ledger (timed = 1 GiB poison fill @6.6 TB/s ~162 us fixed + kernel):
//   R3 ~98 | R4 ~93 (best) | R5 sweep+loads ~124 | R6 256blk ~97
//   R7 builtin-nt ~96 | R8 2-pass ~121 | R9 4-pass ~180 | R10 sc1-nt ~98
// Decomposition: cold first-touch pass ~92 us (2.9 TB/s), warm ~29 us
// (9 TB/s). Compute/LDS/input exonerated. Policy bits measured null.
// Fill writes 1 GiB with FETCH ~14.5 KB -> no RFO on this HW; the 2.3x
// rate gap must be allocation/eviction-stream GEOMETRY.
//
// R12 = clean fill-mimicry (the one untested configuration):
//   - grid-stride over float4 indices, 256 blocks x 256 thr (1024 waves,
//     = fill's concurrency), instantaneous window = 1 contiguous MiB
//     sweeping 256 MiB in 256 steps -> near-sequential L3 victim stream.
//   - inner loop stripped to 2 scalar + 2 vec4 L1/L2-hot loads + 8 fma +
//     1 store, via 3 MB of precomputed per-channel rows in d_ws
//     (s[t][p], a[t][p], b[t][q]; y read directly).
//   - host falls back to R4 kernel if ws_size < 3 MB.
// Pre-committed: dur <=225 geometry confirmed; 255-267 ALL axes exhausted
// -> revert + ROOFLINE next round; >=275 revert + ROOFLINE.

#define N_  8
#define G_  8
#define OG_ 16
#define DX_ 256
#define DY_ 256

typedef float vfloat4 __attribute__((ext_vector_type(4)));

// ---------- precompute: per-channel operand rows into workspace ----------
// sw[t*256+p] = C[g,o] * x[ng,p]
// aw[t*256+p] = wA0*x[ng,p-1] + wA1*x[ng,p+1]
// bw[t*256+q] = wB0*y[ng,q-1] + wB1*y[ng,q+1]
__global__ __launch_bounds__(256) void scvc_precompute(
    const float* __restrict__ x, const float* __restrict__ y,
    const float* __restrict__ C, const float* __restrict__ wA,
    const float* __restrict__ wB,
    float* __restrict__ sw, float* __restrict__ aw, float* __restrict__ bw)
{
    const int t  = blockIdx.x;         // channel 0..1023
    const int i  = threadIdx.x;        // position 0..255
    const int go = t & 127;
    const int ng = ((t >> 7) << 3) | (go >> 4);

    const float  co = C[go];
    const float2 wa = ((const float2*)wA)[go];
    const float2 wb = ((const float2*)wB)[go];

    const float* xrow = x + ng * DX_;
    const float* yrow = y + ng * DY_;

    const float xv = xrow[i];
    const float xl = (i > 0)       ? xrow[i - 1] : 0.0f;
    const float xr = (i < DX_ - 1) ? xrow[i + 1] : 0.0f;
    sw[t * DX_ + i] = co * xv;
    aw[t * DX_ + i] = fmaf(wa.x, xl, wa.y * xr);

    const float yl = (i > 0)       ? yrow[i - 1] : 0.0f;
    const float yr = (i < DY_ - 1) ? yrow[i + 1] : 0.0f;
    bw[t * DY_ + i] = fmaf(wb.x, yl, wb.y * yr);
}

// ---------- main: fill-shaped streaming store pass ----------
__global__ __launch_bounds__(256) void scvc_stream(
    const float* __restrict__ sw,   // (1024*256)
    const float* __restrict__ aw,   // (1024*256)
    const float* __restrict__ bw,   // (1024*256)
    const float* __restrict__ y,    // (64*256)
    float* __restrict__ out)
{
    const int gid = blockIdx.x * 256 + threadIdx.x;   // 0..65535
    vfloat4* out4 = (vfloat4*)out;
    const vfloat4* bw4 = (const vfloat4*)bw;
    const vfloat4* y4p = (const vfloat4*)y;

#pragma unroll 4
    for (int it = 0; it < 256; ++it) {
        const int idx = it * 65536 + gid;   // global float4 index (compact
                                            // 1 MiB window sweeping 256 MiB)
        const int rp = idx >> 6;            // t*256 + p
        const int qv = idx & 63;
        const int t  = idx >> 14;
        const int ng = idx >> 18;

        const float   s  = sw[rp];                   // wave-uniform, L1-hot
        const float   av = aw[rp];                   // wave-uniform, L1-hot
        const vfloat4 b4 = bw4[(t  << 6) | qv];      // L2-hot (1 MB total)
        const vfloat4 yy = y4p[(ng << 6) | qv];      // L1-hot (64 KB total)

        vfloat4 v;
        v.x = fmaf(s, yy.x, av + b4.x);
        v.y = fmaf(s, yy.y, av + b4.y);
        v.z = fmaf(s, yy.z, av + b4.z);
        v.w = fmaf(s, yy.w, av + b4.w);
        out4[idx] = v;
    }
}

// ---------- fallback (R4 structure) if workspace too small ----------
__global__ __launch_bounds__(256) void scvc_kernel_r4(
    const float* __restrict__ x, const float* __restrict__ y,
    const float* __restrict__ C, const float* __restrict__ wA,
    const float* __restrict__ wB, float* __restrict__ out)
{
    __shared__ float sarr[DX_];
    __shared__ float aarr[DX_];
    __shared__ float ybuf[DY_];
    __shared__ float bbuf[DY_];

    const int t    = blockIdx.x >> 1;
    const int half = blockIdx.x & 1;
    const int go   = t & 127;
    const int ng   = ((t >> 7) << 3) | (go >> 4);
    const int tid  = threadIdx.x;

    const float  co = C[go];
    const float2 wa = ((const float2*)wA)[go];
    const float2 wb = ((const float2*)wB)[go];

    const float* xrow = x + ng * DX_;
    const float* yrow = y + ng * DY_;
    {
        float xv = xrow[tid];
        float xl = (tid > 0)       ? xrow[tid - 1] : 0.0f;
        float xr = (tid < DX_ - 1) ? xrow[tid + 1] : 0.0f;
        sarr[tid] = co * xv;
        aarr[tid] = fmaf(wa.x, xl, wa.y * xr);
        float yv = yrow[tid];
        float yl = (tid > 0)       ? yrow[tid - 1] : 0.0f;
        float yr = (tid < DY_ - 1) ? yrow[tid + 1] : 0.0f;
        ybuf[tid] = yv;
        bbuf[tid] = fmaf(wb.x, yl, wb.y * yr);
    }
    __syncthreads();

    const int qv = tid & 63;
    const int wv = tid >> 6;
    const int p0 = half * (DX_ / 2) + wv * 32;
    const vfloat4 y4 = ((const vfloat4*)ybuf)[qv];
    const vfloat4 b4 = ((const vfloat4*)bbuf)[qv];
    float* obase = out + (size_t)t * (DX_ * DY_) + (size_t)p0 * DY_;

#pragma unroll 4
    for (int i = 0; i < 32; ++i) {
        const int p  = p0 + i;
        const float s  = sarr[p];
        const float av = aarr[p];
        vfloat4 v;
        v.x = fmaf(s, y4.x, av + b4.x);
        v.y = fmaf(s, y4.y, av + b4.y);
        v.z = fmaf(s, y4.z, av + b4.z);
        v.w = fmaf(s, y4.w, av + b4.w);
        ((vfloat4*)(obase + (size_t)i * DY_))[qv] = v;
    }
}

extern "C" void kernel_launch(void* const* d_in, const int* in_sizes, int n_in,
                              void* d_out, int out_size, void* d_ws, size_t ws_size,
                              hipStream_t stream) {
    const float* x  = (const float*)d_in[0];
    const float* y  = (const float*)d_in[1];
    const float* C  = (const float*)d_in[2];
    const float* wA = (const float*)d_in[3];
    const float* wB = (const float*)d_in[4];
    float* out = (float*)d_out;

    const size_t nchan = (size_t)N_ * G_ * OG_;        // 1024
    const size_t arr   = nchan * DX_;                  // 262144 floats
    const size_t need  = 3 * arr * sizeof(float);      // 3 MiB

    if (ws_size >= need && d_ws != nullptr) {
        float* sw = (float*)d_ws;
        float* aw = sw + arr;
        float* bw = aw + arr;
        scvc_precompute<<<(int)nchan, 256, 0, stream>>>(x, y, C, wA, wB,
                                                        sw, aw, bw);
        scvc_stream<<<256, 256, 0, stream>>>(sw, aw, bw, y, out);
    } else {
        scvc_kernel_r4<<<N_ * G_ * OG_ * 2, 256, 0, stream>>>(x, y, C, wA, wB,
                                                              out);
    }
}